// Round 1
// baseline (980.517 us; speedup 1.0000x reference)
//
#include <hip/hip_runtime.h>
#include <hip/hip_bf16.h>

#define N_NODES 500000
#define F 128
#define B 20000
#define T 8
#define H1 128
#define H2 64
#define C 32
#define S1 5
#define S2 2

// ---------------------------------------------------------------------------
// K1: PQ[n] = [ x[n]@w_l0 + b_l0 | x[n]@w_r0 + b_r0 ]   (500000 x 256 fp32)
// Tiling: BM=64 rows, BN=256 (full N), BK=32, 256 threads, 8x8 per thread.
// Thread cols: {tx*4..tx*4+3} in P half and {tx*4..tx*4+3} in Q half so that
// LDS reads are contiguous float4 (conflict-free).
// ---------------------------------------------------------------------------
__global__ __launch_bounds__(256) void k1_pq(
    const float* __restrict__ x,
    const float* __restrict__ w_l0, const float* __restrict__ b_l0,
    const float* __restrict__ w_r0, const float* __restrict__ b_r0,
    float* __restrict__ PQ)
{
    __shared__ float At[32][68];    // [k][row], padded to 68 (16B-aligned rows)
    __shared__ float Wt[32][256];   // [k][col]; col<128 = w_l0, col>=128 = w_r0

    const int tid = threadIdx.x;
    const int tx  = tid & 31;       // col group
    const int ty  = tid >> 5;       // row group (0..7), rows ty*8..ty*8+7
    const int m0  = blockIdx.x * 64;

    float acc[8][8];
    #pragma unroll
    for (int i = 0; i < 8; i++)
        #pragma unroll
        for (int j = 0; j < 8; j++) acc[i][j] = 0.f;

    for (int kk = 0; kk < 128; kk += 32) {
        // stage A (transposed): At[k][r] = x[m0+r][kk+k]
        #pragma unroll
        for (int i = 0; i < 2; i++) {
            int lin = tid + i * 256;          // 0..511
            int r   = lin >> 3;               // 0..63
            int c4  = lin & 7;                // float4 chunk within 32-k slab
            int row = m0 + r;
            float4 v = make_float4(0.f, 0.f, 0.f, 0.f);
            if (row < N_NODES)
                v = *(const float4*)(x + (size_t)row * F + kk + c4 * 4);
            At[c4*4+0][r] = v.x; At[c4*4+1][r] = v.y;
            At[c4*4+2][r] = v.z; At[c4*4+3][r] = v.w;
        }
        // stage W: Wt[k][c]
        #pragma unroll
        for (int i = 0; i < 8; i++) {
            int lin = tid + i * 256;          // 0..2047 float4 slots
            int k   = lin >> 6;               // 0..31
            int c   = (lin & 63) * 4;         // 0..252
            float4 v;
            if (c < 128) v = *(const float4*)(w_l0 + (size_t)(kk + k) * 128 + c);
            else         v = *(const float4*)(w_r0 + (size_t)(kk + k) * 128 + (c - 128));
            *(float4*)&Wt[k][c] = v;
        }
        __syncthreads();
        #pragma unroll
        for (int k = 0; k < 32; k++) {
            float4 a0 = *(const float4*)&At[k][ty * 8];
            float4 a1 = *(const float4*)&At[k][ty * 8 + 4];
            float4 w0 = *(const float4*)&Wt[k][tx * 4];
            float4 w1 = *(const float4*)&Wt[k][128 + tx * 4];
            float a[8] = {a0.x, a0.y, a0.z, a0.w, a1.x, a1.y, a1.z, a1.w};
            float w[8] = {w0.x, w0.y, w0.z, w0.w, w1.x, w1.y, w1.z, w1.w};
            #pragma unroll
            for (int r = 0; r < 8; r++)
                #pragma unroll
                for (int c = 0; c < 8; c++)
                    acc[r][c] += a[r] * w[c];
        }
        __syncthreads();
    }

    float4 bl = *(const float4*)(b_l0 + tx * 4);
    float4 br = *(const float4*)(b_r0 + tx * 4);
    #pragma unroll
    for (int r = 0; r < 8; r++) {
        int row = m0 + ty * 8 + r;
        if (row >= N_NODES) break;
        float4 p = make_float4(acc[r][0] + bl.x, acc[r][1] + bl.y,
                               acc[r][2] + bl.z, acc[r][3] + bl.w);
        float4 q = make_float4(acc[r][4] + br.x, acc[r][5] + br.y,
                               acc[r][6] + br.z, acc[r][7] + br.w);
        *(float4*)(PQ + (size_t)row * 256 + tx * 4)       = p;
        *(float4*)(PQ + (size_t)row * 256 + 128 + tx * 4) = q;
    }
}

// ---------------------------------------------------------------------------
// K2: one wave per (b, t). Computes layer-0 currents (6 rows of 128), spikes
// via __ballot (wave-uniform 64-bit masks), then layer-1 as a sparse sum of
// weight rows over set bits. Writes 64 packed layer-1 spike bits per (b,t).
// MODE 0: layer-0 from precomputed PQ gathers.  MODE 1: on-the-fly matvecs.
// ---------------------------------------------------------------------------
__device__ __forceinline__ void mask_walk(unsigned long long m, int par,
                                          const float* __restrict__ w,
                                          int lane, float& acc)
{
    while (m) {
        int i = __builtin_ctzll(m);
        m &= m - 1;
        acc += w[(size_t)(2 * i + par) * H2 + lane];
    }
}

template <int MODE>
__global__ __launch_bounds__(256) void k2_step(
    const float* __restrict__ x,
    const int* __restrict__ nodes, const int* __restrict__ nbr1,
    const int* __restrict__ nbr2,
    const float* __restrict__ w_l0, const float* __restrict__ b_l0,
    const float* __restrict__ w_r0, const float* __restrict__ b_r0,
    const float* __restrict__ w_l1, const float* __restrict__ b_l1,
    const float* __restrict__ w_r1, const float* __restrict__ b_r1,
    const float* __restrict__ PQ,
    unsigned long long* __restrict__ bits)
{
    __shared__ float a_lds[4][F];
    __shared__ float n_lds[4][F];

    const int lane = threadIdx.x & 63;
    const int wv   = threadIdx.x >> 6;
    const int gw   = __builtin_amdgcn_readfirstlane((int)(blockIdx.x * 4 + wv));
    const int b    = gw >> 3;
    const int t    = gw & 7;
    const int c2   = lane * 2;

    const int i_self = nodes[b];
    int i1[S1];
    #pragma unroll
    for (int s = 0; s < S1; s++) i1[s] = nbr1[t * (B * S1) + b * S1 + s];
    int i2[S1 * S2];
    #pragma unroll
    for (int q = 0; q < S1 * S2; q++) i2[q] = nbr2[t * (B * S1 * S2) + b * S1 * S2 + q];

    float accL = 0.f, accR = 0.f;

    if (MODE == 0) {
        // r = 0 (self node): P[self] + 0.2 * sum_s Q[nbr1_s]
        {
            const float* pr = PQ + (size_t)i_self * 256;
            float cx = pr[c2], cy = pr[c2 + 1];
            float qx = 0.f, qy = 0.f;
            #pragma unroll
            for (int s = 0; s < S1; s++) {
                const float* qr = PQ + (size_t)i1[s] * 256 + 128;
                qx += qr[c2]; qy += qr[c2 + 1];
            }
            cx += 0.2f * qx; cy += 0.2f * qy;
            mask_walk(__ballot(cx >= 1.0f), 0, w_l1, lane, accL);
            mask_walk(__ballot(cy >= 1.0f), 1, w_l1, lane, accL);
        }
        // r = 1..5 (hop-1 rows): P[nbr1] + 0.5 * sum_u Q[nbr2_u]
        #pragma unroll
        for (int r = 1; r < 6; r++) {
            const float* pr = PQ + (size_t)i1[r - 1] * 256;
            const float* q0 = PQ + (size_t)i2[(r - 1) * 2] * 256 + 128;
            const float* q1 = PQ + (size_t)i2[(r - 1) * 2 + 1] * 256 + 128;
            float cx = pr[c2]     + 0.5f * (q0[c2]     + q1[c2]);
            float cy = pr[c2 + 1] + 0.5f * (q0[c2 + 1] + q1[c2 + 1]);
            mask_walk(__ballot(cx >= 1.0f), 0, w_r1, lane, accR);
            mask_walk(__ballot(cy >= 1.0f), 1, w_r1, lane, accR);
        }
    } else {
        const float b0x = b_l0[c2] + b_r0[c2];
        const float b0y = b_l0[c2 + 1] + b_r0[c2 + 1];
        float nsx = 0.f, nsy = 0.f;   // running sum of hop-1 rows (for r=0 neigh)
        #pragma unroll 1
        for (int r = 1; r < 6; r++) {
            const float* ar = x + (size_t)i1[r - 1] * F;
            float ax = ar[c2], ay = ar[c2 + 1];
            nsx += ax; nsy += ay;
            const float* ch0 = x + (size_t)i2[(r - 1) * 2] * F;
            const float* ch1 = x + (size_t)i2[(r - 1) * 2 + 1] * F;
            float nx = 0.5f * (ch0[c2]     + ch1[c2]);
            float ny = 0.5f * (ch0[c2 + 1] + ch1[c2 + 1]);
            a_lds[wv][c2] = ax; a_lds[wv][c2 + 1] = ay;
            n_lds[wv][c2] = nx; n_lds[wv][c2 + 1] = ny;
            float cx = b0x, cy = b0y;
            #pragma unroll 4
            for (int k = 0; k < F; k++) {
                float ak = a_lds[wv][k], nk = n_lds[wv][k];
                const float* wl = w_l0 + (size_t)k * H1 + c2;
                const float* wr = w_r0 + (size_t)k * H1 + c2;
                cx += ak * wl[0] + nk * wr[0];
                cy += ak * wl[1] + nk * wr[1];
            }
            mask_walk(__ballot(cx >= 1.0f), 0, w_r1, lane, accR);
            mask_walk(__ballot(cy >= 1.0f), 1, w_r1, lane, accR);
        }
        {
            const float* ar = x + (size_t)i_self * F;
            float ax = ar[c2], ay = ar[c2 + 1];
            a_lds[wv][c2] = ax; a_lds[wv][c2 + 1] = ay;
            n_lds[wv][c2] = 0.2f * nsx; n_lds[wv][c2 + 1] = 0.2f * nsy;
            float cx = b0x, cy = b0y;
            #pragma unroll 4
            for (int k = 0; k < F; k++) {
                float ak = a_lds[wv][k], nk = n_lds[wv][k];
                const float* wl = w_l0 + (size_t)k * H1 + c2;
                const float* wr = w_r0 + (size_t)k * H1 + c2;
                cx += ak * wl[0] + nk * wr[0];
                cy += ak * wl[1] + nk * wr[1];
            }
            mask_walk(__ballot(cx >= 1.0f), 0, w_l1, lane, accL);
            mask_walk(__ballot(cy >= 1.0f), 1, w_l1, lane, accL);
        }
    }

    float cur1 = accL + 0.2f * accR + b_l1[lane] + b_r1[lane];
    unsigned long long sb = __ballot(cur1 >= 1.0f);
    if (lane == 0) bits[(size_t)b * T + t] = sb;
}

// ---------------------------------------------------------------------------
// K3: out[b][c] = b_pool[c] + sum over set spike bits of w_pool[(t*64+j)][c]
// ---------------------------------------------------------------------------
__global__ __launch_bounds__(256) void k3_pool(
    const float* __restrict__ w_pool, const float* __restrict__ b_pool,
    const unsigned long long* __restrict__ bits, float* __restrict__ out)
{
    const int tid = threadIdx.x;
    const int c = tid & 31;
    const int g = tid >> 5;                 // 0..7
    const int b = blockIdx.x * 8 + g;
    if (b >= B) return;
    float acc = b_pool[c];
    #pragma unroll
    for (int t = 0; t < T; t++) {
        unsigned long long m = bits[(size_t)b * T + t];
        while (m) {
            int j = __builtin_ctzll(m);
            m &= m - 1;
            acc += w_pool[(size_t)(t * H2 + j) * C + c];
        }
    }
    out[(size_t)b * C + c] = acc;
}

extern "C" void kernel_launch(void* const* d_in, const int* in_sizes, int n_in,
                              void* d_out, int out_size, void* d_ws, size_t ws_size,
                              hipStream_t stream)
{
    const float* x      = (const float*)d_in[0];
    const int*   nodes  = (const int*)d_in[1];
    const int*   nbr1   = (const int*)d_in[2];
    const int*   nbr2   = (const int*)d_in[3];
    const float* w_l0   = (const float*)d_in[4];
    const float* b_l0   = (const float*)d_in[5];
    const float* w_r0   = (const float*)d_in[6];
    const float* b_r0   = (const float*)d_in[7];
    const float* w_l1   = (const float*)d_in[8];
    const float* b_l1   = (const float*)d_in[9];
    const float* w_r1   = (const float*)d_in[10];
    const float* b_r1   = (const float*)d_in[11];
    const float* w_pool = (const float*)d_in[12];
    const float* b_pool = (const float*)d_in[13];
    float* out = (float*)d_out;

    const size_t pq_bytes   = (size_t)N_NODES * 256 * sizeof(float);          // 512 MB
    const size_t bits_bytes = (size_t)B * T * sizeof(unsigned long long);     // 1.28 MB

    if (ws_size >= pq_bytes + bits_bytes) {
        float* PQ = (float*)d_ws;
        unsigned long long* bits = (unsigned long long*)((char*)d_ws + pq_bytes);
        k1_pq<<<(N_NODES + 63) / 64, 256, 0, stream>>>(x, w_l0, b_l0, w_r0, b_r0, PQ);
        k2_step<0><<<(B * T) / 4, 256, 0, stream>>>(x, nodes, nbr1, nbr2,
            w_l0, b_l0, w_r0, b_r0, w_l1, b_l1, w_r1, b_r1, PQ, bits);
        k3_pool<<<B / 8, 256, 0, stream>>>(w_pool, b_pool, bits, out);
    } else {
        unsigned long long* bits = (unsigned long long*)d_ws;
        k2_step<1><<<(B * T) / 4, 256, 0, stream>>>(x, nodes, nbr1, nbr2,
            w_l0, b_l0, w_r0, b_r0, w_l1, b_l1, w_r1, b_r1, nullptr, bits);
        k3_pool<<<B / 8, 256, 0, stream>>>(w_pool, b_pool, bits, out);
    }
}

// Round 2
// 773.495 us; speedup vs baseline: 1.2676x; 1.2676x over previous
//
#include <hip/hip_runtime.h>
#include <hip/hip_bf16.h>

#define N_NODES 500000
#define F 128
#define B 20000
#define T 8
#define H1 128
#define H2 64
#define C 32
#define S1 5
#define S2 2

// ---------------------------------------------------------------------------
// K1: PQ[n] = [ x[n]@w_l0 + b_l0 | x[n]@w_r0 + b_r0 ]   (500000 x 256 fp32)
// ---------------------------------------------------------------------------
__global__ __launch_bounds__(256) void k1_pq(
    const float* __restrict__ x,
    const float* __restrict__ w_l0, const float* __restrict__ b_l0,
    const float* __restrict__ w_r0, const float* __restrict__ b_r0,
    float* __restrict__ PQ)
{
    __shared__ float At[32][68];    // [k][row], padded
    __shared__ float Wt[32][256];   // [k][col]; col<128 = w_l0, col>=128 = w_r0

    const int tid = threadIdx.x;
    const int tx  = tid & 31;       // col group
    const int ty  = tid >> 5;       // row group (0..7)
    const int m0  = blockIdx.x * 64;

    float acc[8][8];
    #pragma unroll
    for (int i = 0; i < 8; i++)
        #pragma unroll
        for (int j = 0; j < 8; j++) acc[i][j] = 0.f;

    for (int kk = 0; kk < 128; kk += 32) {
        #pragma unroll
        for (int i = 0; i < 2; i++) {
            int lin = tid + i * 256;
            int r   = lin >> 3;
            int c4  = lin & 7;
            int row = m0 + r;
            float4 v = make_float4(0.f, 0.f, 0.f, 0.f);
            if (row < N_NODES)
                v = *(const float4*)(x + (size_t)row * F + kk + c4 * 4);
            At[c4*4+0][r] = v.x; At[c4*4+1][r] = v.y;
            At[c4*4+2][r] = v.z; At[c4*4+3][r] = v.w;
        }
        #pragma unroll
        for (int i = 0; i < 8; i++) {
            int lin = tid + i * 256;
            int k   = lin >> 6;
            int c   = (lin & 63) * 4;
            float4 v;
            if (c < 128) v = *(const float4*)(w_l0 + (size_t)(kk + k) * 128 + c);
            else         v = *(const float4*)(w_r0 + (size_t)(kk + k) * 128 + (c - 128));
            *(float4*)&Wt[k][c] = v;
        }
        __syncthreads();
        #pragma unroll
        for (int k = 0; k < 32; k++) {
            float4 a0 = *(const float4*)&At[k][ty * 8];
            float4 a1 = *(const float4*)&At[k][ty * 8 + 4];
            float4 w0 = *(const float4*)&Wt[k][tx * 4];
            float4 w1 = *(const float4*)&Wt[k][128 + tx * 4];
            float a[8] = {a0.x, a0.y, a0.z, a0.w, a1.x, a1.y, a1.z, a1.w};
            float w[8] = {w0.x, w0.y, w0.z, w0.w, w1.x, w1.y, w1.z, w1.w};
            #pragma unroll
            for (int r = 0; r < 8; r++)
                #pragma unroll
                for (int c = 0; c < 8; c++)
                    acc[r][c] += a[r] * w[c];
        }
        __syncthreads();
    }

    float4 bl = *(const float4*)(b_l0 + tx * 4);
    float4 br = *(const float4*)(b_r0 + tx * 4);
    #pragma unroll
    for (int r = 0; r < 8; r++) {
        int row = m0 + ty * 8 + r;
        if (row >= N_NODES) break;
        float4 p = make_float4(acc[r][0] + bl.x, acc[r][1] + bl.y,
                               acc[r][2] + bl.z, acc[r][3] + bl.w);
        float4 q = make_float4(acc[r][4] + br.x, acc[r][5] + br.y,
                               acc[r][6] + br.z, acc[r][7] + br.w);
        *(float4*)(PQ + (size_t)row * 256 + tx * 4)       = p;
        *(float4*)(PQ + (size_t)row * 256 + 128 + tx * 4) = q;
    }
}

// ---------------------------------------------------------------------------
// K2 v2: one wave per (b,t). Issue ALL 21 scattered row-gathers into named
// registers first (MLP), then ballots, then sparse weight-row walks with
// independent accumulators.
// ---------------------------------------------------------------------------
__device__ __forceinline__ void mask_walk(unsigned long long m, int par,
                                          const float* __restrict__ w,
                                          int lane, float& acc)
{
    while (m) {
        int i = __builtin_ctzll(m);
        m &= m - 1;
        acc += w[(size_t)(2 * i + par) * H2 + lane];
    }
}

template <int MODE>
__global__ __launch_bounds__(256) void k2_step(
    const float* __restrict__ x,
    const int* __restrict__ nodes, const int* __restrict__ nbr1,
    const int* __restrict__ nbr2,
    const float* __restrict__ w_l0, const float* __restrict__ b_l0,
    const float* __restrict__ w_r0, const float* __restrict__ b_r0,
    const float* __restrict__ w_l1, const float* __restrict__ b_l1,
    const float* __restrict__ w_r1, const float* __restrict__ b_r1,
    const float* __restrict__ PQ,
    unsigned long long* __restrict__ bits)
{
    const int lane = threadIdx.x & 63;
    const int wv   = threadIdx.x >> 6;
    const int gw   = __builtin_amdgcn_readfirstlane((int)(blockIdx.x * 4 + wv));
    const int b    = gw >> 3;
    const int t    = gw & 7;
    const int c2   = lane * 2;

    if (MODE == 0) {
        // ---- index loads (scalar) ----
        const int i_self = nodes[b];
        int i1[S1];
        #pragma unroll
        for (int s = 0; s < S1; s++) i1[s] = nbr1[t * (B * S1) + b * S1 + s];
        int i2[S1 * S2];
        #pragma unroll
        for (int q = 0; q < S1 * S2; q++) i2[q] = nbr2[t * (B * S1 * S2) + b * S1 * S2 + q];

        // ---- issue all 21 gathers into registers (no intervening uses) ----
        float2 sp = *(const float2*)(PQ + (size_t)i_self * 256 + c2);
        float2 p1[S1], q1[S1], q2[S1 * S2];
        #pragma unroll
        for (int s = 0; s < S1; s++)
            p1[s] = *(const float2*)(PQ + (size_t)i1[s] * 256 + c2);
        #pragma unroll
        for (int s = 0; s < S1; s++)
            q1[s] = *(const float2*)(PQ + (size_t)i1[s] * 256 + 128 + c2);
        #pragma unroll
        for (int u = 0; u < S1 * S2; u++)
            q2[u] = *(const float2*)(PQ + (size_t)i2[u] * 256 + 128 + c2);

        // ---- ballots ----
        float qsx = 0.f, qsy = 0.f;
        #pragma unroll
        for (int s = 0; s < S1; s++) { qsx += q1[s].x; qsy += q1[s].y; }
        unsigned long long mLx = __ballot(sp.x + 0.2f * qsx >= 1.0f);
        unsigned long long mLy = __ballot(sp.y + 0.2f * qsy >= 1.0f);
        unsigned long long mRx[S1], mRy[S1];
        #pragma unroll
        for (int r = 0; r < S1; r++) {
            float cx = p1[r].x + 0.5f * (q2[2 * r].x + q2[2 * r + 1].x);
            float cy = p1[r].y + 0.5f * (q2[2 * r].y + q2[2 * r + 1].y);
            mRx[r] = __ballot(cx >= 1.0f);
            mRy[r] = __ballot(cy >= 1.0f);
        }

        // ---- sparse layer-1 accumulation, independent chains ----
        float aL0 = 0.f, aL1 = 0.f;
        float aR0 = 0.f, aR1 = 0.f, aR2 = 0.f, aR3 = 0.f;
        mask_walk(mLx, 0, w_l1, lane, aL0);
        mask_walk(mLy, 1, w_l1, lane, aL1);
        mask_walk(mRx[0], 0, w_r1, lane, aR0);
        mask_walk(mRy[0], 1, w_r1, lane, aR1);
        mask_walk(mRx[1], 0, w_r1, lane, aR2);
        mask_walk(mRy[1], 1, w_r1, lane, aR3);
        mask_walk(mRx[2], 0, w_r1, lane, aR0);
        mask_walk(mRy[2], 1, w_r1, lane, aR1);
        mask_walk(mRx[3], 0, w_r1, lane, aR2);
        mask_walk(mRy[3], 1, w_r1, lane, aR3);
        mask_walk(mRx[4], 0, w_r1, lane, aR0);
        mask_walk(mRy[4], 1, w_r1, lane, aR1);

        float cur1 = (aL0 + aL1) + 0.2f * ((aR0 + aR1) + (aR2 + aR3))
                   + b_l1[lane] + b_r1[lane];
        unsigned long long sb = __ballot(cur1 >= 1.0f);
        if (lane == 0) bits[(size_t)b * T + t] = sb;
    } else {
        // fallback: on-the-fly matvecs (only if workspace too small for PQ)
        __shared__ float a_lds[4][F];
        __shared__ float n_lds[4][F];
        const int i_self = nodes[b];
        int i1[S1];
        #pragma unroll
        for (int s = 0; s < S1; s++) i1[s] = nbr1[t * (B * S1) + b * S1 + s];
        int i2[S1 * S2];
        #pragma unroll
        for (int q = 0; q < S1 * S2; q++) i2[q] = nbr2[t * (B * S1 * S2) + b * S1 * S2 + q];

        float accL = 0.f, accR = 0.f;
        const float b0x = b_l0[c2] + b_r0[c2];
        const float b0y = b_l0[c2 + 1] + b_r0[c2 + 1];
        float nsx = 0.f, nsy = 0.f;
        #pragma unroll 1
        for (int r = 1; r < 6; r++) {
            const float* ar = x + (size_t)i1[r - 1] * F;
            float ax = ar[c2], ay = ar[c2 + 1];
            nsx += ax; nsy += ay;
            const float* ch0 = x + (size_t)i2[(r - 1) * 2] * F;
            const float* ch1 = x + (size_t)i2[(r - 1) * 2 + 1] * F;
            float nx = 0.5f * (ch0[c2]     + ch1[c2]);
            float ny = 0.5f * (ch0[c2 + 1] + ch1[c2 + 1]);
            a_lds[wv][c2] = ax; a_lds[wv][c2 + 1] = ay;
            n_lds[wv][c2] = nx; n_lds[wv][c2 + 1] = ny;
            float cx = b0x, cy = b0y;
            #pragma unroll 4
            for (int k = 0; k < F; k++) {
                float ak = a_lds[wv][k], nk = n_lds[wv][k];
                const float* wl = w_l0 + (size_t)k * H1 + c2;
                const float* wr = w_r0 + (size_t)k * H1 + c2;
                cx += ak * wl[0] + nk * wr[0];
                cy += ak * wl[1] + nk * wr[1];
            }
            mask_walk(__ballot(cx >= 1.0f), 0, w_r1, lane, accR);
            mask_walk(__ballot(cy >= 1.0f), 1, w_r1, lane, accR);
        }
        {
            const float* ar = x + (size_t)i_self * F;
            float ax = ar[c2], ay = ar[c2 + 1];
            a_lds[wv][c2] = ax; a_lds[wv][c2 + 1] = ay;
            n_lds[wv][c2] = 0.2f * nsx; n_lds[wv][c2 + 1] = 0.2f * nsy;
            float cx = b0x, cy = b0y;
            #pragma unroll 4
            for (int k = 0; k < F; k++) {
                float ak = a_lds[wv][k], nk = n_lds[wv][k];
                const float* wl = w_l0 + (size_t)k * H1 + c2;
                const float* wr = w_r0 + (size_t)k * H1 + c2;
                cx += ak * wl[0] + nk * wr[0];
                cy += ak * wl[1] + nk * wr[1];
            }
            mask_walk(__ballot(cx >= 1.0f), 0, w_l1, lane, accL);
            mask_walk(__ballot(cy >= 1.0f), 1, w_l1, lane, accL);
        }
        float cur1 = accL + 0.2f * accR + b_l1[lane] + b_r1[lane];
        unsigned long long sb = __ballot(cur1 >= 1.0f);
        if (lane == 0) bits[(size_t)b * T + t] = sb;
    }
}

// ---------------------------------------------------------------------------
// K3: out[b][c] = b_pool[c] + sum over set spike bits of w_pool[(t*64+j)][c]
// ---------------------------------------------------------------------------
__global__ __launch_bounds__(256) void k3_pool(
    const float* __restrict__ w_pool, const float* __restrict__ b_pool,
    const unsigned long long* __restrict__ bits, float* __restrict__ out)
{
    const int tid = threadIdx.x;
    const int c = tid & 31;
    const int g = tid >> 5;
    const int b = blockIdx.x * 8 + g;
    if (b >= B) return;
    float acc = b_pool[c];
    #pragma unroll
    for (int t = 0; t < T; t++) {
        unsigned long long m = bits[(size_t)b * T + t];
        while (m) {
            int j = __builtin_ctzll(m);
            m &= m - 1;
            acc += w_pool[(size_t)(t * H2 + j) * C + c];
        }
    }
    out[(size_t)b * C + c] = acc;
}

extern "C" void kernel_launch(void* const* d_in, const int* in_sizes, int n_in,
                              void* d_out, int out_size, void* d_ws, size_t ws_size,
                              hipStream_t stream)
{
    const float* x      = (const float*)d_in[0];
    const int*   nodes  = (const int*)d_in[1];
    const int*   nbr1   = (const int*)d_in[2];
    const int*   nbr2   = (const int*)d_in[3];
    const float* w_l0   = (const float*)d_in[4];
    const float* b_l0   = (const float*)d_in[5];
    const float* w_r0   = (const float*)d_in[6];
    const float* b_r0   = (const float*)d_in[7];
    const float* w_l1   = (const float*)d_in[8];
    const float* b_l1   = (const float*)d_in[9];
    const float* w_r1   = (const float*)d_in[10];
    const float* b_r1   = (const float*)d_in[11];
    const float* w_pool = (const float*)d_in[12];
    const float* b_pool = (const float*)d_in[13];
    float* out = (float*)d_out;

    const size_t pq_bytes   = (size_t)N_NODES * 256 * sizeof(float);
    const size_t bits_bytes = (size_t)B * T * sizeof(unsigned long long);

    if (ws_size >= pq_bytes + bits_bytes) {
        float* PQ = (float*)d_ws;
        unsigned long long* bits = (unsigned long long*)((char*)d_ws + pq_bytes);
        k1_pq<<<(N_NODES + 63) / 64, 256, 0, stream>>>(x, w_l0, b_l0, w_r0, b_r0, PQ);
        k2_step<0><<<(B * T) / 4, 256, 0, stream>>>(x, nodes, nbr1, nbr2,
            w_l0, b_l0, w_r0, b_r0, w_l1, b_l1, w_r1, b_r1, PQ, bits);
        k3_pool<<<B / 8, 256, 0, stream>>>(w_pool, b_pool, bits, out);
    } else {
        unsigned long long* bits = (unsigned long long*)d_ws;
        k2_step<1><<<(B * T) / 4, 256, 0, stream>>>(x, nodes, nbr1, nbr2,
            w_l0, b_l0, w_r0, b_r0, w_l1, b_l1, w_r1, b_r1, nullptr, bits);
        k3_pool<<<B / 8, 256, 0, stream>>>(w_pool, b_pool, bits, out);
    }
}